// Round 1
// baseline (561.676 us; speedup 1.0000x reference)
//
#include <hip/hip_runtime.h>
#include <cstdint>
#include <cstddef>

// Problem constants
#define Bsz   32
#define Ssz   2048
#define Tsz   768
#define NH    8
#define DH    96
#define DHID  384
#define Mrows (Bsz*Ssz)     // 65536
#define Ncols (NH*DH)       // 768

using u16 = unsigned short;
typedef __bf16 bf16x8 __attribute__((ext_vector_type(8)));
typedef float  f32x4  __attribute__((ext_vector_type(4)));

__device__ __forceinline__ u16 f2b(float f) {
  uint32_t x = __builtin_bit_cast(uint32_t, f);
  uint32_t r = (x + 0x7FFFu + ((x >> 16) & 1u)) >> 16;   // RNE
  return (u16)r;
}
__device__ __forceinline__ float b2f(u16 u) {
  return __builtin_bit_cast(float, (uint32_t)u << 16);
}

// ---------------------------------------------------------------------------
// Kernel 1: pack weights to bf16, transposed so MFMA B-frags are contiguous in K
//   B1t[n][k]  (n = h*96+d, k in [0,768))  <- P_w[h][k][d]
//   W1t[h][n][k] (n<384, k<96)             <- W1_w[h][k][n]
//   W2t[h][n][k] (n<96,  k<384)            <- W2_w[h][k][n]
// ---------------------------------------------------------------------------
__global__ __launch_bounds__(256) void k_pack(const float* __restrict__ Pw,
    const float* __restrict__ W1w, const float* __restrict__ W2w,
    u16* __restrict__ B1t, u16* __restrict__ W1t, u16* __restrict__ W2t)
{
  int i = blockIdx.x * 256 + threadIdx.x;
  if (i < 589824) {
    int n = i / 768, k = i % 768;
    int h = n / 96, d = n % 96;
    B1t[i] = f2b(Pw[(size_t)h*73728 + (size_t)k*96 + d]);
  } else if (i < 589824 + 294912) {
    int j = i - 589824;
    int h = j / 36864, r = j % 36864;
    int n = r / 96, k = r % 96;
    W1t[j] = f2b(W1w[(size_t)h*36864 + (size_t)k*384 + n]);
  } else if (i < 589824 + 2*294912) {
    int q = i - 589824 - 294912;
    int h = q / 36864, r = q % 36864;
    int n = r / 384, k = r % 384;
    W2t[q] = f2b(W2w[(size_t)h*36864 + (size_t)k*96 + n]);
  }
}

// ---------------------------------------------------------------------------
// Kernel 2: Hi[65536][768] (bf16) = emb(fp32->bf16) @ B1 + P_b
// 128x128 tile, BK=32, 4 waves (2x2), mfma_f32_16x16x32_bf16
// ---------------------------------------------------------------------------
__global__ __launch_bounds__(256) void k_gemm1(const float* __restrict__ emb,
    const u16* __restrict__ B1t, const float* __restrict__ Pb, u16* __restrict__ Hi)
{
  __shared__ u16 As[128][40];   // +8 pad: row stride 80B -> conflict-free b128 reads
  __shared__ u16 Bs[128][40];   // B^T tile [n][k]
  const int tid  = threadIdx.x;
  const int lane = tid & 63;
  const int wid  = tid >> 6;
  const int wr = wid >> 1, wc = wid & 1;
  const int bm = blockIdx.x, bn = blockIdx.y;
  const int l15 = lane & 15, lg = lane >> 4;

  f32x4 acc[4][4] = {};
  for (int kt = 0; kt < Tsz/32; ++kt) {
    const int k0 = kt * 32;
    // stage A: 128 rows x 32 k, fp32 -> bf16 (coalesced 16B granules)
    #pragma unroll
    for (int i = 0; i < 4; ++i) {
      int g = tid + i*256;
      int row = g >> 3, seg = g & 7;
      float4 v = *reinterpret_cast<const float4*>(
          emb + (size_t)(bm*128 + row)*Tsz + k0 + seg*4);
      u16 tmp[4] = { f2b(v.x), f2b(v.y), f2b(v.z), f2b(v.w) };
      *reinterpret_cast<uint2*>(&As[row][seg*4]) = *reinterpret_cast<uint2*>(tmp);
    }
    // stage B: 128 n x 32 k bf16
    #pragma unroll
    for (int i = 0; i < 2; ++i) {
      int g = tid + i*256;
      int row = g >> 2, seg = g & 3;
      uint4 v = *reinterpret_cast<const uint4*>(
          B1t + (size_t)(bn*128 + row)*Tsz + k0 + seg*8);
      *reinterpret_cast<uint4*>(&Bs[row][seg*8]) = v;
    }
    __syncthreads();
    bf16x8 a[4], b[4];
    #pragma unroll
    for (int r = 0; r < 4; ++r)
      a[r] = *reinterpret_cast<const bf16x8*>(&As[wr*64 + r*16 + l15][lg*8]);
    #pragma unroll
    for (int c = 0; c < 4; ++c)
      b[c] = *reinterpret_cast<const bf16x8*>(&Bs[wc*64 + c*16 + l15][lg*8]);
    #pragma unroll
    for (int r = 0; r < 4; ++r)
      #pragma unroll
      for (int c = 0; c < 4; ++c)
        acc[r][c] = __builtin_amdgcn_mfma_f32_16x16x32_bf16(a[r], b[c], acc[r][c], 0, 0, 0);
    __syncthreads();
  }
  // epilogue: bias + bf16 store (C layout: col=lane&15, row=(lane>>4)*4+j)
  #pragma unroll
  for (int c = 0; c < 4; ++c) {
    int col = bn*128 + wc*64 + c*16 + l15;
    float bias = Pb[col];
    #pragma unroll
    for (int r = 0; r < 4; ++r) {
      int row0 = bm*128 + wr*64 + r*16 + lg*4;
      #pragma unroll
      for (int j = 0; j < 4; ++j)
        Hi[(size_t)(row0 + j)*Ncols + col] = f2b(acc[r][c][j] + bias);
    }
  }
}

// ---------------------------------------------------------------------------
// Kernel 3: fused FFN + online-softmax partials.
// Grid (chunk=32, h=8, b=32); block 256 (4 waves); 64 rows per block.
//  phase1: Z[64][384] = relu(HiS[64][96] @ W1 + b1)  (wave w: 6 n-tiles)
//  phase2: logits[16 rows/wave][96] = Z @ W2 + b2
//  then per-column online softmax partial (m,l,acc) over the 64 rows.
// ---------------------------------------------------------------------------
__global__ __launch_bounds__(256) void k_ffn_pool(
    const u16* __restrict__ Hi, const u16* __restrict__ W1t, const u16* __restrict__ W2t,
    const float* __restrict__ b1, const float* __restrict__ b2v, const float* __restrict__ mask,
    float* __restrict__ Pm, float* __restrict__ Pl, float* __restrict__ Pa)
{
  __shared__ u16 HiS[64][104];   // 13312 B
  __shared__ u16 Zs[64][392];    // 50176 B (row stride 784B, 16B-mult)
  __shared__ float lm[64];
  const int tid = threadIdx.x, lane = tid & 63, w = tid >> 6;
  const int l15 = lane & 15, lg = lane >> 4;
  const int chunk = blockIdx.x, h = blockIdx.y, b = blockIdx.z;
  const size_t row0 = (size_t)b * Ssz + (size_t)chunk * 64;

  if (tid < 64) lm[tid] = logf(mask[row0 + tid]);
  // stage Hi chunk: 64 rows x 96 bf16
  for (int i = tid; i < 64*12; i += 256) {
    int r = i / 12, seg = i % 12;
    uint4 v = *reinterpret_cast<const uint4*>(Hi + (row0 + r)*Ncols + h*DH + seg*8);
    *reinterpret_cast<uint4*>(&HiS[r][seg*8]) = v;
  }
  __syncthreads();

  // phase 1
  bf16x8 afr[4][3];
  #pragma unroll
  for (int rt = 0; rt < 4; ++rt)
    #pragma unroll
    for (int ks = 0; ks < 3; ++ks)
      afr[rt][ks] = *reinterpret_cast<const bf16x8*>(&HiS[rt*16 + l15][ks*32 + lg*8]);
  const u16* W1h = W1t + (size_t)h * DHID * DH;
  #pragma unroll
  for (int nt6 = 0; nt6 < 6; ++nt6) {
    int ncol = (w*6 + nt6)*16 + l15;           // 0..383
    bf16x8 bfr[3];
    #pragma unroll
    for (int ks = 0; ks < 3; ++ks)
      bfr[ks] = *reinterpret_cast<const bf16x8*>(W1h + (size_t)ncol*DH + ks*32 + lg*8);
    f32x4 z[4] = {};
    #pragma unroll
    for (int ks = 0; ks < 3; ++ks)
      #pragma unroll
      for (int rt = 0; rt < 4; ++rt)
        z[rt] = __builtin_amdgcn_mfma_f32_16x16x32_bf16(afr[rt][ks], bfr[ks], z[rt], 0, 0, 0);
    float bias = b1[h*DHID + ncol];
    #pragma unroll
    for (int rt = 0; rt < 4; ++rt)
      #pragma unroll
      for (int j = 0; j < 4; ++j)
        Zs[rt*16 + lg*4 + j][ncol] = f2b(fmaxf(z[rt][j] + bias, 0.f));
  }
  __syncthreads();

  // phase 2: wave w owns rows w*16..w*16+15, all 96 cols
  const u16* W2h = W2t + (size_t)h * DH * DHID;
  f32x4 lgt[6] = {};
  #pragma unroll
  for (int ks = 0; ks < 12; ++ks) {
    bf16x8 a2 = *reinterpret_cast<const bf16x8*>(&Zs[w*16 + l15][ks*32 + lg*8]);
    #pragma unroll
    for (int ct = 0; ct < 6; ++ct) {
      bf16x8 bf = *reinterpret_cast<const bf16x8*>(W2h + (size_t)(ct*16 + l15)*DHID + ks*32 + lg*8);
      lgt[ct] = __builtin_amdgcn_mfma_f32_16x16x32_bf16(a2, bf, lgt[ct], 0, 0, 0);
    }
  }
  __syncthreads();   // Zs reads done; it will be overlaid below

  float* mb = reinterpret_cast<float*>(&Zs[0][0]);   // [4][96] each
  float* lb = mb + 4*96;
  float* ab = lb + 4*96;
  #pragma unroll
  for (int ct = 0; ct < 6; ++ct) {
    int col = ct*16 + l15;                 // d in [0,96)
    float bias2 = b2v[h*DH + col];
    float av[4];
    float mloc = -3.4e38f;
    #pragma unroll
    for (int j = 0; j < 4; ++j) {
      int rl = w*16 + lg*4 + j;
      av[j] = lgt[ct][j] + bias2 + lm[rl];
      mloc = fmaxf(mloc, av[j]);
    }
    mloc = fmaxf(mloc, __shfl_xor(mloc, 16));
    mloc = fmaxf(mloc, __shfl_xor(mloc, 32));
    float ll = 0.f, aa = 0.f;
    #pragma unroll
    for (int j = 0; j < 4; ++j) {
      int rl = w*16 + lg*4 + j;
      float p = __expf(av[j] - mloc);
      ll += p;
      aa += p * b2f(HiS[rl][col]);
    }
    ll += __shfl_xor(ll, 16); ll += __shfl_xor(ll, 32);
    aa += __shfl_xor(aa, 16); aa += __shfl_xor(aa, 32);
    if (lane < 16) {
      mb[w*96 + col] = mloc;
      lb[w*96 + col] = ll;
      ab[w*96 + col] = aa;
    }
  }
  __syncthreads();
  if (tid < 96) {
    float m = fmaxf(fmaxf(mb[tid], mb[96+tid]), fmaxf(mb[192+tid], mb[288+tid]));
    float l = 0.f, a = 0.f;
    #pragma unroll
    for (int q = 0; q < 4; ++q) {
      float sc = __expf(mb[q*96 + tid] - m);
      l += lb[q*96 + tid] * sc;
      a += ab[q*96 + tid] * sc;
    }
    size_t pidx = (((size_t)(b*NH + h)*32 + chunk)*96) + tid;
    Pm[pidx] = m; Pl[pidx] = l; Pa[pidx] = a;
  }
}

// ---------------------------------------------------------------------------
// Kernel 4: merge 32 chunk partials per (b,h,d) -> out[b][h*96+d]
// ---------------------------------------------------------------------------
__global__ __launch_bounds__(256) void k_merge(const float* __restrict__ Pm,
    const float* __restrict__ Pl, const float* __restrict__ Pa, float* __restrict__ out)
{
  int idx = blockIdx.x * 256 + threadIdx.x;
  if (idx >= Bsz*NH*DH) return;
  int d = idx % 96;
  int bh = idx / 96;
  const float* pm = Pm + (size_t)bh*32*96 + d;
  const float* pl = Pl + (size_t)bh*32*96 + d;
  const float* pa = Pa + (size_t)bh*32*96 + d;
  float m = -3.4e38f;
  #pragma unroll
  for (int c = 0; c < 32; ++c) m = fmaxf(m, pm[c*96]);
  float l = 0.f, a = 0.f;
  #pragma unroll
  for (int c = 0; c < 32; ++c) {
    float sc = __expf(pm[c*96] - m);
    l += pl[c*96] * sc;
    a += pa[c*96] * sc;
  }
  out[idx] = a / l;
}

// ---------------------------------------------------------------------------
// Workspace layout (bytes), total ~112.5 MB:
//   Hi  bf16 : 0          .. 100663296
//   B1t bf16 : 100663296  (1179648)
//   W1t bf16 : 101842944  (589824)
//   W2t bf16 : 102432768  (589824)
//   Pm  f32  : 103022592  (3145728)
//   Pl  f32  : 106168320  (3145728)
//   Pa  f32  : 109314048  (3145728)
// ---------------------------------------------------------------------------
extern "C" void kernel_launch(void* const* d_in, const int* in_sizes, int n_in,
                              void* d_out, int out_size, void* d_ws, size_t ws_size,
                              hipStream_t stream)
{
  const float* emb  = (const float*)d_in[0];
  const float* mask = (const float*)d_in[1];
  const float* Pw   = (const float*)d_in[2];
  const float* Pb   = (const float*)d_in[3];
  const float* W1w  = (const float*)d_in[4];
  const float* W1b  = (const float*)d_in[5];
  const float* W2w  = (const float*)d_in[6];
  const float* W2b  = (const float*)d_in[7];
  float* out = (float*)d_out;

  char* ws = (char*)d_ws;
  u16*   Hi  = (u16*)(ws);
  u16*   B1t = (u16*)(ws + 100663296ull);
  u16*   W1t = (u16*)(ws + 101842944ull);
  u16*   W2t = (u16*)(ws + 102432768ull);
  float* Pm  = (float*)(ws + 103022592ull);
  float* Pl  = (float*)(ws + 106168320ull);
  float* Pa  = (float*)(ws + 109314048ull);

  k_pack<<<dim3(4608), dim3(256), 0, stream>>>(Pw, W1w, W2w, B1t, W1t, W2t);
  k_gemm1<<<dim3(512, 6), dim3(256), 0, stream>>>(emb, B1t, Pb, Hi);
  k_ffn_pool<<<dim3(32, 8, 32), dim3(256), 0, stream>>>(Hi, W1t, W2t, W1b, W2b, mask, Pm, Pl, Pa);
  k_merge<<<dim3(96), dim3(256), 0, stream>>>(Pm, Pl, Pa, out);
}

// Round 2
// 402.516 us; speedup vs baseline: 1.3954x; 1.3954x over previous
//
#include <hip/hip_runtime.h>
#include <cstdint>
#include <cstddef>

// Problem constants
#define Bsz   32
#define Ssz   2048
#define Tsz   768
#define NH    8
#define DH    96
#define DHID  384
#define Ncols (NH*DH)       // 768

using u16 = unsigned short;
typedef __bf16 bf16x8 __attribute__((ext_vector_type(8)));
typedef float  f32x4  __attribute__((ext_vector_type(4)));

__device__ __forceinline__ u16 f2b(float f) {
  uint32_t x = __builtin_bit_cast(uint32_t, f);
  uint32_t r = (x + 0x7FFFu + ((x >> 16) & 1u)) >> 16;   // RNE
  return (u16)r;
}
__device__ __forceinline__ float b2f(u16 u) {
  return __builtin_bit_cast(float, (uint32_t)u << 16);
}
__device__ __forceinline__ uint32_t pack2(float lo, float hi) {
  return (uint32_t)f2b(lo) | ((uint32_t)f2b(hi) << 16);
}

// ---------------------------------------------------------------------------
// Kernel 1: pack weights to bf16, transposed so MFMA frags are contiguous in K
//   B1t[n][k]  (n = h*96+d, k in [0,768))  <- P_w[h][k][d]
//   W1t[h][n][k] (n<384, k<96)             <- W1_w[h][k][n]
//   W2t[h][n][k] (n<96,  k<384)            <- W2_w[h][k][n]
// ---------------------------------------------------------------------------
__global__ __launch_bounds__(256) void k_pack(const float* __restrict__ Pw,
    const float* __restrict__ W1w, const float* __restrict__ W2w,
    u16* __restrict__ B1t, u16* __restrict__ W1t, u16* __restrict__ W2t)
{
  int i = blockIdx.x * 256 + threadIdx.x;
  if (i < 589824) {
    int n = i / 768, k = i % 768;
    int h = n / 96, d = n % 96;
    B1t[i] = f2b(Pw[(size_t)h*73728 + (size_t)k*96 + d]);
  } else if (i < 589824 + 294912) {
    int j = i - 589824;
    int h = j / 36864, r = j % 36864;
    int n = r / 96, k = r % 96;
    W1t[j] = f2b(W1w[(size_t)h*36864 + (size_t)k*384 + n]);
  } else if (i < 589824 + 2*294912) {
    int q = i - 589824 - 294912;
    int h = q / 36864, r = q % 36864;
    int n = r / 384, k = r % 384;
    W2t[q] = f2b(W2w[(size_t)h*36864 + (size_t)k*96 + n]);
  }
}

// ---------------------------------------------------------------------------
// Kernel 2: Hi[65536][768] (bf16) = emb(fp32->bf16) @ B1 + P_b
// 128x128 tile, BK=32, 4 waves (2x2), mfma_f32_16x16x32_bf16.
// 1-D grid + bijective XCD-chunked swizzle: each XCD owns 64 consecutive
// bm panels so the 6 bn-sharers of an A-panel hit the same L2.
// ---------------------------------------------------------------------------
__global__ __launch_bounds__(256) void k_gemm1(const float* __restrict__ emb,
    const u16* __restrict__ B1t, const float* __restrict__ Pb, u16* __restrict__ Hi)
{
  __shared__ u16 As[128][40];   // +8 pad: conflict-free b128 reads
  __shared__ u16 Bs[128][40];
  const int tid  = threadIdx.x;
  const int lane = tid & 63;
  const int wid  = tid >> 6;
  const int wr = wid >> 1, wc = wid & 1;
  const int L = blockIdx.x;                 // 0..3071
  const int widx = (L & 7) * 384 + (L >> 3);
  const int bm = widx / 6, bn = widx % 6;
  const int l15 = lane & 15, lg = lane >> 4;

  f32x4 acc[4][4] = {};
  for (int kt = 0; kt < Tsz/32; ++kt) {
    const int k0 = kt * 32;
    #pragma unroll
    for (int i = 0; i < 4; ++i) {
      int g = tid + i*256;
      int row = g >> 3, seg = g & 7;
      float4 v = *reinterpret_cast<const float4*>(
          emb + (size_t)(bm*128 + row)*Tsz + k0 + seg*4);
      u16 tmp[4] = { f2b(v.x), f2b(v.y), f2b(v.z), f2b(v.w) };
      *reinterpret_cast<uint2*>(&As[row][seg*4]) = *reinterpret_cast<uint2*>(tmp);
    }
    #pragma unroll
    for (int i = 0; i < 2; ++i) {
      int g = tid + i*256;
      int row = g >> 2, seg = g & 3;
      uint4 v = *reinterpret_cast<const uint4*>(
          B1t + (size_t)(bn*128 + row)*Tsz + k0 + seg*8);
      *reinterpret_cast<uint4*>(&Bs[row][seg*8]) = v;
    }
    __syncthreads();
    bf16x8 a[4], b[4];
    #pragma unroll
    for (int r = 0; r < 4; ++r)
      a[r] = *reinterpret_cast<const bf16x8*>(&As[wr*64 + r*16 + l15][lg*8]);
    #pragma unroll
    for (int c = 0; c < 4; ++c)
      b[c] = *reinterpret_cast<const bf16x8*>(&Bs[wc*64 + c*16 + l15][lg*8]);
    #pragma unroll
    for (int r = 0; r < 4; ++r)
      #pragma unroll
      for (int c = 0; c < 4; ++c)
        acc[r][c] = __builtin_amdgcn_mfma_f32_16x16x32_bf16(a[r], b[c], acc[r][c], 0, 0, 0);
    __syncthreads();
  }
  #pragma unroll
  for (int c = 0; c < 4; ++c) {
    int col = bn*128 + wc*64 + c*16 + l15;
    float bias = Pb[col];
    #pragma unroll
    for (int r = 0; r < 4; ++r) {
      int row0 = bm*128 + wr*64 + r*16 + lg*4;
      #pragma unroll
      for (int j = 0; j < 4; ++j)
        Hi[(size_t)(row0 + j)*Ncols + col] = f2b(acc[r][c][j] + bias);
    }
  }
}

// ---------------------------------------------------------------------------
// Kernel 3 (v2): barrier-free fused FFN + online-softmax partials.
// Grid (chunk=16, h=8, b=32); block 256 = 4 waves; 128 rows/block,
// 32 rows (2 strips of 16) per wave, waves independent after Hi stage.
//
// Phase 1 (swapped): D = mfma(A=W1^T-frag, B=Hi-frag) -> lane holds
//   Z[row=l15][n = c*32 + t*16 + lg*4 + reg]  (4 consecutive n -> b64 LDS write)
// Bounce through 1.25KB/wave LDS strip, read back b128 as phase-2 A-frag:
//   Z[row=l15][k = c*32 + lg*8 + j]
// Phase 2: D = mfma(A=Z-frag, B=W2-frag) -> lane holds
//   L[row = lg*4+reg][d = ct*16 + l15]  -> in-register column softmax partials.
// ---------------------------------------------------------------------------
__global__ __launch_bounds__(256) void k_ffn_pool(
    const u16* __restrict__ Hi, const u16* __restrict__ W1t, const u16* __restrict__ W2t,
    const float* __restrict__ b1, const float* __restrict__ b2v, const float* __restrict__ mask,
    float* __restrict__ Pm, float* __restrict__ Pl, float* __restrict__ Pa)
{
  __shared__ u16 HiS[128][104];     // 26624 B (stride 208B: 16B-aligned rows)
  __shared__ u16 Zb[4][16][40];     // 5120 B per-wave Z bounce (stride 80B)
  __shared__ float lm[128];
  __shared__ float mb[4][96], lb[4][96], ab[4][96];   // 4608 B

  const int tid = threadIdx.x, lane = tid & 63, w = tid >> 6;
  const int l15 = lane & 15, lg = lane >> 4;
  const int chunk = blockIdx.x, h = blockIdx.y, b = blockIdx.z;
  const size_t row0 = (size_t)b * Ssz + (size_t)chunk * 128;

  if (tid < 128) lm[tid] = logf(mask[row0 + tid]);
  for (int i = tid; i < 128*12; i += 256) {
    int r = i / 12, seg = i % 12;
    uint4 v = *reinterpret_cast<const uint4*>(Hi + (row0 + r)*Ncols + h*DH + seg*8);
    *reinterpret_cast<uint4*>(&HiS[r][seg*8]) = v;
  }
  __syncthreads();

  const u16* W1h = W1t + (size_t)h * DHID * DH;
  const u16* W2h = W2t + (size_t)h * DH * DHID;
  const float* b1h = b1 + h * DHID;

  // Hi B-frags for this wave's two strips (rows w*32 .. w*32+31)
  bf16x8 hifr[2][3];
  #pragma unroll
  for (int ls = 0; ls < 2; ++ls)
    #pragma unroll
    for (int ks = 0; ks < 3; ++ks)
      hifr[ls][ks] = *reinterpret_cast<const bf16x8*>(
          &HiS[(w*2 + ls)*16 + l15][ks*32 + lg*8]);

  f32x4 lgt[2][6] = {};

  #pragma unroll 1
  for (int c = 0; c < 12; ++c) {      // 12 chunks of 32 n-values
    // W1 A-frags for the chunk's two 16-n tiles (shared by both strips)
    bf16x8 a1[2][3];
    #pragma unroll
    for (int t = 0; t < 2; ++t)
      #pragma unroll
      for (int ks = 0; ks < 3; ++ks)
        a1[t][ks] = *reinterpret_cast<const bf16x8*>(
            W1h + (size_t)(c*32 + t*16 + l15)*DH + ks*32 + lg*8);
    // W2 B-frags for k-slice c (shared by both strips)
    bf16x8 b2f_[6];
    #pragma unroll
    for (int ct = 0; ct < 6; ++ct)
      b2f_[ct] = *reinterpret_cast<const bf16x8*>(
          W2h + (size_t)(ct*16 + l15)*DHID + c*32 + lg*8);
    float4 bia0 = *reinterpret_cast<const float4*>(b1h + c*32 + lg*4);
    float4 bia1 = *reinterpret_cast<const float4*>(b1h + c*32 + 16 + lg*4);

    #pragma unroll
    for (int ls = 0; ls < 2; ++ls) {
      f32x4 z0 = {}, z1 = {};
      #pragma unroll
      for (int ks = 0; ks < 3; ++ks) {
        z0 = __builtin_amdgcn_mfma_f32_16x16x32_bf16(a1[0][ks], hifr[ls][ks], z0, 0, 0, 0);
        z1 = __builtin_amdgcn_mfma_f32_16x16x32_bf16(a1[1][ks], hifr[ls][ks], z1, 0, 0, 0);
      }
      uint2 w0, w1;
      w0.x = pack2(fmaxf(z0[0] + bia0.x, 0.f), fmaxf(z0[1] + bia0.y, 0.f));
      w0.y = pack2(fmaxf(z0[2] + bia0.z, 0.f), fmaxf(z0[3] + bia0.w, 0.f));
      w1.x = pack2(fmaxf(z1[0] + bia1.x, 0.f), fmaxf(z1[1] + bia1.y, 0.f));
      w1.y = pack2(fmaxf(z1[2] + bia1.z, 0.f), fmaxf(z1[3] + bia1.w, 0.f));
      *reinterpret_cast<uint2*>(&Zb[w][l15][lg*4])      = w0;   // tile0 cols
      *reinterpret_cast<uint2*>(&Zb[w][l15][16 + lg*4]) = w1;   // tile1 cols
      bf16x8 zfrag = *reinterpret_cast<const bf16x8*>(&Zb[w][l15][lg*8]);
      #pragma unroll
      for (int ct = 0; ct < 6; ++ct)
        lgt[ls][ct] = __builtin_amdgcn_mfma_f32_16x16x32_bf16(zfrag, b2f_[ct], lgt[ls][ct], 0, 0, 0);
    }
  }

  // ---- per-wave tail: column softmax partials over this wave's 32 rows ----
  float b2s[6];
  #pragma unroll
  for (int ct = 0; ct < 6; ++ct) b2s[ct] = b2v[h*DH + ct*16 + l15];

  float fm[6], fl[6], fa[6];
  #pragma unroll
  for (int ct = 0; ct < 6; ++ct) {
    float mm[2], ll[2], aa[2];
    #pragma unroll
    for (int ls = 0; ls < 2; ++ls) {
      const int s = w*2 + ls;
      float4 lmv = *reinterpret_cast<const float4*>(&lm[s*16 + lg*4]);
      float av0 = lgt[ls][ct][0] + b2s[ct] + lmv.x;
      float av1 = lgt[ls][ct][1] + b2s[ct] + lmv.y;
      float av2 = lgt[ls][ct][2] + b2s[ct] + lmv.z;
      float av3 = lgt[ls][ct][3] + b2s[ct] + lmv.w;
      float m = fmaxf(fmaxf(av0, av1), fmaxf(av2, av3));
      m = fmaxf(m, __shfl_xor(m, 16));
      m = fmaxf(m, __shfl_xor(m, 32));
      float p0 = __expf(av0 - m), p1 = __expf(av1 - m);
      float p2 = __expf(av2 - m), p3 = __expf(av3 - m);
      float h0 = b2f(HiS[s*16 + lg*4 + 0][ct*16 + l15]);
      float h1 = b2f(HiS[s*16 + lg*4 + 1][ct*16 + l15]);
      float h2 = b2f(HiS[s*16 + lg*4 + 2][ct*16 + l15]);
      float h3 = b2f(HiS[s*16 + lg*4 + 3][ct*16 + l15]);
      float l = (p0 + p1) + (p2 + p3);
      float a = (p0*h0 + p1*h1) + (p2*h2 + p3*h3);
      l += __shfl_xor(l, 16); l += __shfl_xor(l, 32);
      a += __shfl_xor(a, 16); a += __shfl_xor(a, 32);
      mm[ls] = m; ll[ls] = l; aa[ls] = a;
    }
    float M  = fmaxf(mm[0], mm[1]);
    float e0 = __expf(mm[0] - M), e1 = __expf(mm[1] - M);
    fm[ct] = M;
    fl[ct] = ll[0]*e0 + ll[1]*e1;
    fa[ct] = aa[0]*e0 + aa[1]*e1;
  }
  if (lane < 16) {
    #pragma unroll
    for (int ct = 0; ct < 6; ++ct) {
      mb[w][ct*16 + l15] = fm[ct];
      lb[w][ct*16 + l15] = fl[ct];
      ab[w][ct*16 + l15] = fa[ct];
    }
  }
  __syncthreads();
  if (tid < 96) {
    float m = fmaxf(fmaxf(mb[0][tid], mb[1][tid]), fmaxf(mb[2][tid], mb[3][tid]));
    float l = 0.f, a = 0.f;
    #pragma unroll
    for (int q = 0; q < 4; ++q) {
      float sc = __expf(mb[q][tid] - m);
      l += lb[q][tid] * sc;
      a += ab[q][tid] * sc;
    }
    size_t pidx = (((size_t)(b*NH + h)*16 + chunk)*96) + tid;
    Pm[pidx] = m; Pl[pidx] = l; Pa[pidx] = a;
  }
}

// ---------------------------------------------------------------------------
// Kernel 4: merge 16 chunk partials per (b,h,d) -> out[b][h*96+d]
// ---------------------------------------------------------------------------
__global__ __launch_bounds__(256) void k_merge(const float* __restrict__ Pm,
    const float* __restrict__ Pl, const float* __restrict__ Pa, float* __restrict__ out)
{
  int idx = blockIdx.x * 256 + threadIdx.x;
  if (idx >= Bsz*NH*DH) return;
  int d = idx % 96;
  int bh = idx / 96;
  const float* pm = Pm + (size_t)bh*16*96 + d;
  const float* pl = Pl + (size_t)bh*16*96 + d;
  const float* pa = Pa + (size_t)bh*16*96 + d;
  float m = -3.4e38f;
  #pragma unroll
  for (int c = 0; c < 16; ++c) m = fmaxf(m, pm[c*96]);
  float l = 0.f, a = 0.f;
  #pragma unroll
  for (int c = 0; c < 16; ++c) {
    float sc = __expf(pm[c*96] - m);
    l += pl[c*96] * sc;
    a += pa[c*96] * sc;
  }
  out[idx] = a / l;
}

// ---------------------------------------------------------------------------
// Workspace layout (bytes), total ~107.7 MB:
//   Hi  bf16 : 0           (100663296)
//   B1t bf16 : 100663296   (1179648)
//   W1t bf16 : 101842944   (589824)
//   W2t bf16 : 102432768   (589824)
//   Pm  f32  : 103022592   (1572864)
//   Pl  f32  : 104595456   (1572864)
//   Pa  f32  : 106168320   (1572864)
// ---------------------------------------------------------------------------
extern "C" void kernel_launch(void* const* d_in, const int* in_sizes, int n_in,
                              void* d_out, int out_size, void* d_ws, size_t ws_size,
                              hipStream_t stream)
{
  const float* emb  = (const float*)d_in[0];
  const float* mask = (const float*)d_in[1];
  const float* Pw   = (const float*)d_in[2];
  const float* Pb   = (const float*)d_in[3];
  const float* W1w  = (const float*)d_in[4];
  const float* W1b  = (const float*)d_in[5];
  const float* W2w  = (const float*)d_in[6];
  const float* W2b  = (const float*)d_in[7];
  float* out = (float*)d_out;

  char* ws = (char*)d_ws;
  u16*   Hi  = (u16*)(ws);
  u16*   B1t = (u16*)(ws + 100663296ull);
  u16*   W1t = (u16*)(ws + 101842944ull);
  u16*   W2t = (u16*)(ws + 102432768ull);
  float* Pm  = (float*)(ws + 103022592ull);
  float* Pl  = (float*)(ws + 104595456ull);
  float* Pa  = (float*)(ws + 106168320ull);

  k_pack<<<dim3(4608), dim3(256), 0, stream>>>(Pw, W1w, W2w, B1t, W1t, W2t);
  k_gemm1<<<dim3(3072), dim3(256), 0, stream>>>(emb, B1t, Pb, Hi);
  k_ffn_pool<<<dim3(16, 8, 32), dim3(256), 0, stream>>>(Hi, W1t, W2t, W1b, W2b, mask, Pm, Pl, Pa);
  k_merge<<<dim3(96), dim3(256), 0, stream>>>(Pm, Pl, Pa, out);
}